// Round 9
// baseline (474.495 us; speedup 1.0000x reference)
//
#include <hip/hip_runtime.h>

// Fused: LayerNorm -> QKV proj -> per-head attention (diag masked) -> out proj
// B=2, N=2048, D=1024, H=16, dh=64. bf16 MFMA 16x16x32 everywhere.
// R9: attn kv-split=4 + f32 atomicAdd accumulation (fixed-offset softmax =>
//     partials are purely additive). 1024 blocks, 25KB LDS single-buffer ->
//     4 blocks/CU = 4 waves/SIMD WITH s=4 K/V amortization (R6 had waves but
//     2.5x traffic; R8 had traffic but half the waves). Oaccum f32 [bh][d][q],
//     zero kernel before attn, combine = transpose-normalize.

#define DIMM   1024
#define NSEQ   2048
#define BATCH  2
#define HEADS  16
#define DHEAD  64
#define QKVN   3072
#define MROWS  4096   // BATCH*NSEQ

typedef float          f32x4  __attribute__((ext_vector_type(4)));
typedef __bf16         bf16x8 __attribute__((ext_vector_type(8)));
typedef __bf16         bf16x4 __attribute__((ext_vector_type(4)));
typedef unsigned short u16x8  __attribute__((ext_vector_type(8)));
typedef unsigned short u16x4  __attribute__((ext_vector_type(4)));

// SCALE * log2(e): fold into q so softmax uses exp2 directly.
#define QSCALE (0.125f * 1.4426950408889634f)

#if __has_builtin(__builtin_amdgcn_exp2f)
#define EXP2(x) __builtin_amdgcn_exp2f(x)
#else
#define EXP2(x) exp2f(x)
#endif

__device__ __forceinline__ unsigned short f2bf(float f) {
  unsigned u = __builtin_bit_cast(unsigned, f);
  u += 0x7FFFu + ((u >> 16) & 1u);   // round-to-nearest-even
  return (unsigned short)(u >> 16);
}
__device__ __forceinline__ bf16x8 as_bf(u16x8 v) { return __builtin_bit_cast(bf16x8, v); }

// f32x4 -> 4 bf16 (RNE)
__device__ __forceinline__ u16x4 cvt4(f32x4 v) {
  bf16x4 b;
  b[0] = (__bf16)v[0]; b[1] = (__bf16)v[1]; b[2] = (__bf16)v[2]; b[3] = (__bf16)v[3];
  return __builtin_bit_cast(u16x4, b);
}

// async global->LDS, 16B per lane; LDS dest = wave-uniform base + lane*16
__device__ __forceinline__ void gl_lds16(const unsigned short* g, unsigned short* l) {
  __builtin_amdgcn_global_load_lds(
      (const __attribute__((address_space(1))) unsigned*)g,
      (__attribute__((address_space(3))) unsigned*)l, 16, 0, 0);
}

// swizzled b128 fragment read from an unpadded [rows][64] bf16 tile:
// LDS chunk c at row r holds global chunk c ^ (r&7).
__device__ __forceinline__ bf16x8 lds_frag(const unsigned short* base, int row, int chunk) {
  return as_bf(*(const u16x8*)&base[row * 64 + ((chunk ^ (row & 7)) << 3)]);
}

// ---------------- weight transpose tile + fp32->bf16: dst[c][r] = src[r][c]
__device__ __forceinline__ void transpose_tile(
    const float* __restrict__ src, unsigned short* __restrict__ dst,
    int R, int C, int bx, int by, int tid) {
  __shared__ float t[32][33];
  const int rb = by * 32, cb = bx * 32;
  const int r0 = tid >> 5;   // 0..7
  const int c  = tid & 31;
#pragma unroll
  for (int i = 0; i < 4; ++i)
    t[r0 + i * 8][c] = src[(rb + r0 + i * 8) * C + cb + c];
  __syncthreads();
#pragma unroll
  for (int i = 0; i < 4; ++i)
    dst[(cb + r0 + i * 8) * R + rb + c] = f2bf(t[c][r0 + i * 8]);
}

// ---------------- prep: LN (blocks 0..4095) + weight transposes (4096..8191)
__global__ __launch_bounds__(256) void prep_kernel(
    const float* __restrict__ x, const float* __restrict__ g,
    const float* __restrict__ be, const float* __restrict__ w_qkv,
    const float* __restrict__ w_out, unsigned short* __restrict__ xn,
    unsigned short* __restrict__ wqkvT, unsigned short* __restrict__ woutT) {
  const int bid = blockIdx.x, tid = threadIdx.x;
  if (bid < MROWS) {
    // LayerNorm: one row (1024) per 256-thread block, bf16 out
    const int row = bid;
    const int wave = tid >> 6, lane = tid & 63;
    const float4 v = *(const float4*)&x[row * DIMM + tid * 4];
    float s  = v.x + v.y + v.z + v.w;
    float s2 = v.x * v.x + v.y * v.y + v.z * v.z + v.w * v.w;
#pragma unroll
    for (int o = 32; o >= 1; o >>= 1) { s += __shfl_xor(s, o); s2 += __shfl_xor(s2, o); }
    __shared__ float ps[4], ps2[4];
    if (lane == 0) { ps[wave] = s; ps2[wave] = s2; }
    __syncthreads();
    s  = ps[0] + ps[1] + ps[2] + ps[3];
    s2 = ps2[0] + ps2[1] + ps2[2] + ps2[3];
    const float mu  = s * (1.0f / DIMM);
    const float var = s2 * (1.0f / DIMM) - mu * mu;
    const float rs  = rsqrtf(var + 1e-5f);
    const float4 gg = *(const float4*)&g[tid * 4];
    const float4 bb = *(const float4*)&be[tid * 4];
    u16x4 o;
    o[0] = f2bf((v.x - mu) * rs * gg.x + bb.x);
    o[1] = f2bf((v.y - mu) * rs * gg.y + bb.y);
    o[2] = f2bf((v.z - mu) * rs * gg.z + bb.z);
    o[3] = f2bf((v.w - mu) * rs * gg.w + bb.w);
    *(u16x4*)&xn[row * DIMM + tid * 4] = o;
  } else {
    const int t = bid - MROWS;            // 0..4095
    const int bx = t & 127, by = t >> 7;  // 128 x 32
    if (bx < QKVN / 32) transpose_tile(w_qkv, wqkvT, DIMM, QKVN, bx, by, tid);
    else                transpose_tile(w_out, woutT, DIMM, DIMM, bx - QKVN / 32, by, tid);
  }
}

// ---------------- merged QKV GEMM: 128x128 tiles, single-buffer 32KB LDS,
// 3 blocks/CU co-resident (grid 768). bn 0..15 -> q/k (C^T), 16..23 -> v (C).
__global__ __launch_bounds__(256, 3) void gemm_qkv_kernel(
    const unsigned short* __restrict__ A, const unsigned short* __restrict__ Bt,
    unsigned short* __restrict__ qb, unsigned short* __restrict__ kb,
    unsigned short* __restrict__ vtb) {
  __shared__ __attribute__((aligned(16))) unsigned short As[128 * 64];  // 16 KB
  __shared__ __attribute__((aligned(16))) unsigned short Bs[128 * 64];  // 16 KB
  const int tid = threadIdx.x;
  const int bm = blockIdx.y, bn = blockIdx.x;
  const int lane = tid & 63, wave = tid >> 6;
  const int l15 = lane & 15, quad = lane >> 4;
  const int wm = wave >> 1, wn = wave & 1;
  const int lrow = lane >> 3;
  const int gcol = ((lane & 7) ^ lrow) << 3;
  const unsigned short* Ab = A  + (bm * 128 + wave * 32 + lrow) * DIMM + gcol;
  const unsigned short* Bb = Bt + (bn * 128 + wave * 32 + lrow) * DIMM + gcol;
  const bool swap = (bn < 16);
  f32x4 acc[4][4] = {};

  for (int k0 = 0; k0 < DIMM; k0 += 64) {
#pragma unroll
    for (int j = 0; j < 4; ++j) {
      gl_lds16(Ab + j * 8 * DIMM + k0, &As[(wave * 32 + j * 8) * 64]);
      gl_lds16(Bb + j * 8 * DIMM + k0, &Bs[(wave * 32 + j * 8) * 64]);
    }
    __syncthreads();
#pragma unroll
    for (int kk = 0; kk < 2; ++kk) {
      bf16x8 af[4], bfr[4];
#pragma unroll
      for (int mi = 0; mi < 4; ++mi) af[mi]  = lds_frag(As, wm * 64 + mi * 16 + l15, kk * 4 + quad);
#pragma unroll
      for (int ni = 0; ni < 4; ++ni) bfr[ni] = lds_frag(Bs, wn * 64 + ni * 16 + l15, kk * 4 + quad);
      if (swap) {
#pragma unroll
        for (int mi = 0; mi < 4; ++mi)
#pragma unroll
          for (int ni = 0; ni < 4; ++ni)
            acc[mi][ni] = __builtin_amdgcn_mfma_f32_16x16x32_bf16(bfr[ni], af[mi], acc[mi][ni], 0, 0, 0);
      } else {
#pragma unroll
        for (int mi = 0; mi < 4; ++mi)
#pragma unroll
          for (int ni = 0; ni < 4; ++ni)
            acc[mi][ni] = __builtin_amdgcn_mfma_f32_16x16x32_bf16(af[mi], bfr[ni], acc[mi][ni], 0, 0, 0);
      }
    }
    __syncthreads();
  }

  if (swap) {
    // q/k blocks: C^T -> reg r runs along weight col (dd) -> b64 stores.
    const int colbase = bn * 128 + wn * 64;        // wave-uniform
    const int which = colbase >> 10;               // 0=q, 1=k
    unsigned short* dst = which ? kb : qb;
    const float sc = which ? 1.0f : QSCALE;
#pragma unroll
    for (int mi = 0; mi < 4; ++mi) {
      const int m = bm * 128 + wm * 64 + mi * 16 + l15;   // xn row
      const int bh0 = (m >> 11) * HEADS;
      const int n = m & 2047;
#pragma unroll
      for (int ni = 0; ni < 4; ++ni) {
        const int wc = (colbase & 1023) + ni * 16 + quad * 4;  // r-contig
        const int h = wc >> 6, dd = wc & 63;
        f32x4 v = acc[mi][ni] * sc;
        *(u16x4*)&dst[((bh0 + h) * NSEQ + n) * DHEAD + dd] = cvt4(v);
      }
    }
  } else {
    // v blocks: C -> reg r runs along n -> b64 stores to vt.
    const int colbase = bn * 128 + wn * 64 - 2048;   // v col base, 0..1023
#pragma unroll
    for (int mi = 0; mi < 4; ++mi) {
      const int m0 = bm * 128 + wm * 64 + mi * 16 + quad * 4;   // n, r-contig
      const int bh0 = (m0 >> 11) * HEADS;
      const int n0 = m0 & 2047;
#pragma unroll
      for (int ni = 0; ni < 4; ++ni) {
        const int vcol = colbase + ni * 16 + l15;
        const int h = vcol >> 6, dd = vcol & 63;
        *(u16x4*)&vtb[((bh0 + h) * DHEAD + dd) * NSEQ + n0] = cvt4(acc[mi][ni]);
      }
    }
  }
}

// ---------------- zero: Oaccum (16 MB) + laccum (256 KB)
__global__ __launch_bounds__(256) void zero_kernel(
    float* __restrict__ oacc, float* __restrict__ lacc) {
  const int bid = blockIdx.x, tid = threadIdx.x;
  const f32x4 z = {0.f, 0.f, 0.f, 0.f};
  if (bid < 4096) *(f32x4*)&oacc[(bid * 256 + tid) * 4] = z;
  else            *(f32x4*)&lacc[((bid - 4096) * 256 + tid) * 4] = z;
}

// ---------------- flash attention, transposed-S, fixed-offset softmax.
// block = (bh, 256-q tile, kv-quarter). 4 waves x 64 q rows (4 subtiles),
// K/V fragments read once per iter feed 64 MFMAs (s=4). kv-split=4 =>
// grid 1024 = 4 blocks/CU = 4 waves/SIMD. Single-buffer 25KB LDS.
// Partials accumulate via f32 atomicAdd into Oaccum [bh][d][q] + laccum.
__global__ __launch_bounds__(256, 4) void attn_kernel(
    const unsigned short* __restrict__ qb, const unsigned short* __restrict__ kb,
    const unsigned short* __restrict__ vtb,
    float* __restrict__ oacc, float* __restrict__ lacc) {
  __shared__ __attribute__((aligned(16))) unsigned short Ks[64 * 64];   // swizzled, 8 KB
  __shared__ __attribute__((aligned(16))) unsigned short Vts[64 * 64];  // swizzled, 8 KB
  __shared__ __attribute__((aligned(16))) unsigned short Ps[4][16][72]; // per-wave, 9 KB
  const int tid = threadIdx.x, wave = tid >> 6, lane = tid & 63;
  const int l15 = lane & 15, quad = lane >> 4;
  const int bh = blockIdx.x, qt = blockIdx.y, z = blockIdx.z;
  const int qbase = qt * 256 + wave * 64;   // this wave's 64 q rows

  // Q fragments (B-operand layout: n=l15=q, k=quad*8+j), q pre-scaled
  bf16x8 aq[4][2];
#pragma unroll
  for (int sub = 0; sub < 4; ++sub) {
    const unsigned short* qrow = qb + (bh * NSEQ + qbase + sub * 16 + l15) * DHEAD;
    aq[sub][0] = as_bf(*(const u16x8*)(qrow + quad * 8));
    aq[sub][1] = as_bf(*(const u16x8*)(qrow + 32 + quad * 8));
  }

  float lsum[4] = {};
  f32x4 occ[4][4] = {};   // O^T per sub: d = ct*16+quad*4+r, q = l15

  // staging: wave w stages rows w*16..w*16+15 of K and of Vt (2 instrs each)
  const int lrow = lane >> 3;
  const int gcol = ((lane & 7) ^ lrow) << 3;
  const unsigned short* Kb = kb  + (bh * NSEQ + wave * 16 + lrow) * DHEAD + gcol;
  const unsigned short* Vb = vtb + (bh * DHEAD + wave * 16 + lrow) * NSEQ + gcol;

  const int it0 = z * 8, it1 = it0 + 8;   // this block's kv-tile quarter

  // the single kv-iter (global tile index) containing this wave's diagonal
  const int diag_it = qt * 4 + wave;
  const bool diag_lane = ((l15 >> 2) == quad);   // quad*4+r == l15 solvable
  const int diag_r = l15 & 3;

  for (int it = it0; it < it1; ++it) {
    gl_lds16(Kb + it * 64 * DHEAD,             &Ks[(wave * 16) * 64]);
    gl_lds16(Kb + it * 64 * DHEAD + 8 * DHEAD, &Ks[(wave * 16 + 8) * 64]);
    gl_lds16(Vb + it * 64,                     &Vts[(wave * 16) * 64]);
    gl_lds16(Vb + it * 64 + 8 * NSEQ,          &Vts[(wave * 16 + 8) * 64]);
    __syncthreads();   // drain async loads (all waves)

    // K/V fragments: read once, feed all 4 q-subtiles
    bf16x8 ak[2][4], av[2][4];
#pragma unroll
    for (int kk = 0; kk < 2; ++kk)
#pragma unroll
      for (int ct = 0; ct < 4; ++ct) {
        ak[kk][ct] = lds_frag(Ks,  ct * 16 + l15, kk * 4 + quad);
        av[kk][ct] = lds_frag(Vts, ct * 16 + l15, kk * 4 + quad);
      }
#pragma unroll
    for (int sub = 0; sub < 4; ++sub) {
      // S^T - 32 : col=l15=q, row=quad*4+r=kv offset (per ct tile of 16)
      f32x4 scc[4];
#pragma unroll
      for (int ct = 0; ct < 4; ++ct) scc[ct] = (f32x4){-32.f, -32.f, -32.f, -32.f};
#pragma unroll
      for (int kk = 0; kk < 2; ++kk)
#pragma unroll
        for (int ct = 0; ct < 4; ++ct)
          scc[ct] = __builtin_amdgcn_mfma_f32_16x16x32_bf16(ak[kk][ct], aq[sub][kk], scc[ct], 0, 0, 0);
#pragma unroll
      for (int ct = 0; ct < 4; ++ct)
#pragma unroll
        for (int r = 0; r < 4; ++r) scc[ct][r] = EXP2(scc[ct][r]);

      // diagonal mask: kv_off = sub*16 + l15 lives at ct==sub, r==l15&3 on
      // lanes with quad == l15>>2. Zero BEFORE summing.
      if (it == diag_it && diag_lane) scc[sub][diag_r] = 0.f;

      f32x4 ps4 = (scc[0] + scc[1]) + (scc[2] + scc[3]);
      lsum[sub] += (ps4[0] + ps4[1]) + (ps4[2] + ps4[3]);

      // P[q][kv] -> LDS (wave-private slice; subs reuse it, same-wave in-order)
#pragma unroll
      for (int ct = 0; ct < 4; ++ct)
        *(u16x4*)&Ps[wave][l15][ct * 16 + quad * 4] = cvt4(scc[ct]);

      // O^T += V^T P^T : A=Vt (m=d,k=kv), B=P (n=q,k=kv)
#pragma unroll
      for (int kk = 0; kk < 2; ++kk) {
        bf16x8 bp = as_bf(*(const u16x8*)&Ps[wave][l15][kk * 32 + quad * 8]);
#pragma unroll
        for (int ct = 0; ct < 4; ++ct)
          occ[sub][ct] = __builtin_amdgcn_mfma_f32_16x16x32_bf16(av[kk][ct], bp, occ[sub][ct], 0, 0, 0);
      }
    }
    __syncthreads();   // all waves done reading Ks/Vts before next staging
  }
  // epilogue: atomic-accumulate UNNORMALIZED partial O^T (f32) + partial l.
  float* obase = oacc + (size_t)bh * 64 * NSEQ;
#pragma unroll
  for (int sub = 0; sub < 4; ++sub) {
    float l = lsum[sub];
    l += __shfl_xor(l, 16);
    l += __shfl_xor(l, 32);
    const int qg = qbase + sub * 16 + l15;
    if (quad == 0) atomicAdd(&lacc[bh * NSEQ + qg], l);
#pragma unroll
    for (int ct = 0; ct < 4; ++ct)
#pragma unroll
      for (int r = 0; r < 4; ++r)
        atomicAdd(&obase[(ct * 16 + quad * 4 + r) * NSEQ + qg], occ[sub][ct][r]);
  }
}

// ---------------- combine: Oaccum [bh][d][q] f32 -> attn bf16 [b*N+q][h*64+d],
// normalized by laccum. 64x64 transpose tile per block. Grid (32 bh, 32 qtile).
__global__ __launch_bounds__(256) void combine_kernel(
    const float* __restrict__ oacc, const float* __restrict__ lacc,
    unsigned short* __restrict__ attnb) {
  __shared__ float Ls[64][65];
  __shared__ float Lr[64];
  const int bh = blockIdx.x, qt = blockIdx.y;
  const int b = bh >> 4, h = bh & 15;
  const int tid = threadIdx.x;
  const int tq = tid & 63, td = tid >> 6;   // td 0..3
  const int q0 = qt * 64;
  const float* src = oacc + (size_t)bh * 64 * NSEQ + q0;
  if (tid < 64) Lr[tid] = lacc[bh * NSEQ + q0 + tid];
#pragma unroll
  for (int i = 0; i < 16; ++i) {
    const int d = td * 16 + i;
    Ls[d][tq] = src[d * NSEQ + tq];
  }
  __syncthreads();
#pragma unroll
  for (int i = 0; i < 16; ++i) {
    const int q = td * 16 + i;
    const float rl = __builtin_amdgcn_rcpf(Lr[q]);
    attnb[(b * NSEQ + q0 + q) * DIMM + h * DHEAD + tq] = f2bf(Ls[tq][q] * rl);
  }
}

// ---------------- output projection (C^T): [4096,1024] @ woutT[1024,1024] -> fp32
// M64 x N128 tiles -> grid (8,64)=512 blocks; double-buffered single-barrier K.
__global__ __launch_bounds__(256, 2) void gemm_out_kernel(
    const unsigned short* __restrict__ A,   // attn bf16 [4096,1024]
    const unsigned short* __restrict__ Bt,  // woutT bf16 [1024,1024]
    float* __restrict__ out) {
  __shared__ __attribute__((aligned(16))) unsigned short As[2 * 64 * 64];   // 16 KB
  __shared__ __attribute__((aligned(16))) unsigned short Bs[2 * 128 * 64];  // 32 KB
  const int tid = threadIdx.x;
  const int bm = blockIdx.y, bn = blockIdx.x;
  const int lane = tid & 63, wave = tid >> 6;
  const int l15 = lane & 15, quad = lane >> 4;
  const int wm = wave >> 1, wn = wave & 1;
  const int lrow = lane >> 3;
  const int gcol = ((lane & 7) ^ lrow) << 3;
  const unsigned short* Ab = A  + (bm * 64 + wave * 16 + lrow) * DIMM + gcol;
  const unsigned short* Bb = Bt + (bn * 128 + wave * 32 + lrow) * DIMM + gcol;
  f32x4 acc[2][4] = {};

  // prologue: stage k-tile 0 into buffer 0
#pragma unroll
  for (int j = 0; j < 2; ++j) gl_lds16(Ab + j * 8 * DIMM, &As[(wave * 16 + j * 8) * 64]);
#pragma unroll
  for (int j = 0; j < 4; ++j) gl_lds16(Bb + j * 8 * DIMM, &Bs[(wave * 32 + j * 8) * 64]);

  for (int it = 0; it < DIMM / 64; ++it) {
    const int cur = it & 1;
    __syncthreads();
    if (it < DIMM / 64 - 1) {
      const int k0 = (it + 1) * 64;
      unsigned short* An = &As[(cur ^ 1) * 4096];
      unsigned short* Bn = &Bs[(cur ^ 1) * 8192];
#pragma unroll
      for (int j = 0; j < 2; ++j) gl_lds16(Ab + j * 8 * DIMM + k0, &An[(wave * 16 + j * 8) * 64]);
#pragma unroll
      for (int j = 0; j < 4; ++j) gl_lds16(Bb + j * 8 * DIMM + k0, &Bn[(wave * 32 + j * 8) * 64]);
    }
    const unsigned short* Ac = &As[cur * 4096];
    const unsigned short* Bc = &Bs[cur * 8192];
#pragma unroll
    for (int kk = 0; kk < 2; ++kk) {
      bf16x8 af[2], bfr[4];
#pragma unroll
      for (int mi = 0; mi < 2; ++mi) af[mi]  = lds_frag(Ac, wm * 32 + mi * 16 + l15, kk * 4 + quad);
#pragma unroll
      for (int ni = 0; ni < 4; ++ni) bfr[ni] = lds_frag(Bc, wn * 64 + ni * 16 + l15, kk * 4 + quad);
#pragma unroll
      for (int mi = 0; mi < 2; ++mi)
#pragma unroll
        for (int ni = 0; ni < 4; ++ni)
          acc[mi][ni] = __builtin_amdgcn_mfma_f32_16x16x32_bf16(bfr[ni], af[mi], acc[mi][ni], 0, 0, 0);
    }
  }
  // C^T epilogue: col=l15 -> out row m; row(quad*4+r, r-contig) -> out col.
#pragma unroll
  for (int mi = 0; mi < 2; ++mi) {
    const int m = bm * 64 + wm * 32 + mi * 16 + l15;   // attn row
#pragma unroll
    for (int ni = 0; ni < 4; ++ni) {
      const int col = bn * 128 + wn * 64 + ni * 16 + quad * 4;  // r-contig
      *(f32x4*)&out[m * DIMM + col] = acc[mi][ni];
    }
  }
}

extern "C" void kernel_launch(void* const* d_in, const int* in_sizes, int n_in,
                              void* d_out, int out_size, void* d_ws, size_t ws_size,
                              hipStream_t stream) {
  const float* x     = (const float*)d_in[0];
  const float* gamma = (const float*)d_in[1];
  const float* beta  = (const float*)d_in[2];
  const float* w_qkv = (const float*)d_in[3];  // [1024, 3072]
  const float* w_out = (const float*)d_in[4];  // [1024, 1024]
  float* out = (float*)d_out;

  char* ws = (char*)d_ws;
  // layout (48 MB budget):
  // [0,8)   xn (dead after qkv)      -> Oaccum f32 [0,16) during attn
  // [8,14)  wqkvT (dead after qkv)
  // [16,24) qbuf (dead after attn)   -> combined attn bf16
  // [24,32) kbuf  [32,40) vtbuf
  // [40,42) woutT  [42,42.25) laccum f32
  unsigned short* xn    = (unsigned short*)(ws);
  unsigned short* wqkvT = (unsigned short*)(ws + 8388608);
  unsigned short* qbuf  = (unsigned short*)(ws + 16777216);
  unsigned short* kbuf  = (unsigned short*)(ws + 25165824);
  unsigned short* vtbuf = (unsigned short*)(ws + 33554432);
  unsigned short* woutT = (unsigned short*)(ws + 41943040);
  float*          oacc  = (float*)(ws);                      // 16 MB
  float*          lacc  = (float*)(ws + 44040192);           // 256 KB
  unsigned short* attnb = qbuf;                              // reuse dead qbuf

  prep_kernel<<<MROWS + (QKVN + DIMM) / 32 * (DIMM / 32), 256, 0, stream>>>(
      x, gamma, beta, w_qkv, w_out, xn, wqkvT, woutT);
  gemm_qkv_kernel<<<dim3(24, MROWS / 128), 256, 0, stream>>>(xn, wqkvT, qbuf, kbuf, vtbuf);
  zero_kernel<<<4096 + 64, 256, 0, stream>>>(oacc, lacc);
  attn_kernel<<<dim3(BATCH * HEADS, NSEQ / 256, 4), 256, 0, stream>>>(qbuf, kbuf, vtbuf, oacc, lacc);
  combine_kernel<<<dim3(BATCH * HEADS, NSEQ / 64), 256, 0, stream>>>(oacc, lacc, attnb);
  gemm_out_kernel<<<dim3(DIMM / 128, MROWS / 64), 256, 0, stream>>>(attnb, woutT, out);
}

// Round 10
// 183.066 us; speedup vs baseline: 2.5919x; 2.5919x over previous
//
#include <hip/hip_runtime.h>

// Fused: LayerNorm -> QKV proj -> per-head attention (diag masked) -> out proj
// B=2, N=2048, D=1024, H=16, dh=64. bf16 MFMA 16x16x32 everywhere.
// R10: consolidation. attn = R5 version (53us, best known; R7/R8/R9 variants
//     all neutral-or-worse; atomics catastrophic per R9's 1.6GB HBM counter).
//     gemm_out -> BK=128 single-buffer (8 K-iters, 32 MFMA/wave/barrier, 2x
//     work per barrier drain), 4-bit XOR swizzle, grid 512 = 2/CU exact.

#define DIMM   1024
#define NSEQ   2048
#define BATCH  2
#define HEADS  16
#define DHEAD  64
#define QKVN   3072
#define MROWS  4096   // BATCH*NSEQ

typedef float          f32x4  __attribute__((ext_vector_type(4)));
typedef __bf16         bf16x8 __attribute__((ext_vector_type(8)));
typedef __bf16         bf16x4 __attribute__((ext_vector_type(4)));
typedef unsigned short u16x8  __attribute__((ext_vector_type(8)));
typedef unsigned short u16x4  __attribute__((ext_vector_type(4)));

// SCALE * log2(e): fold into q so softmax uses exp2 directly.
#define QSCALE (0.125f * 1.4426950408889634f)

#if __has_builtin(__builtin_amdgcn_exp2f)
#define EXP2(x) __builtin_amdgcn_exp2f(x)
#else
#define EXP2(x) exp2f(x)
#endif

__device__ __forceinline__ unsigned short f2bf(float f) {
  unsigned u = __builtin_bit_cast(unsigned, f);
  u += 0x7FFFu + ((u >> 16) & 1u);   // round-to-nearest-even
  return (unsigned short)(u >> 16);
}
__device__ __forceinline__ bf16x8 as_bf(u16x8 v) { return __builtin_bit_cast(bf16x8, v); }

// f32x4 -> 4 bf16 (RNE)
__device__ __forceinline__ u16x4 cvt4(f32x4 v) {
  bf16x4 b;
  b[0] = (__bf16)v[0]; b[1] = (__bf16)v[1]; b[2] = (__bf16)v[2]; b[3] = (__bf16)v[3];
  return __builtin_bit_cast(u16x4, b);
}

// async global->LDS, 16B per lane; LDS dest = wave-uniform base + lane*16
__device__ __forceinline__ void gl_lds16(const unsigned short* g, unsigned short* l) {
  __builtin_amdgcn_global_load_lds(
      (const __attribute__((address_space(1))) unsigned*)g,
      (__attribute__((address_space(3))) unsigned*)l, 16, 0, 0);
}

// swizzled b128 fragment read from an unpadded [rows][64] bf16 tile:
// LDS chunk c at row r holds global chunk c ^ (r&7).
__device__ __forceinline__ bf16x8 lds_frag(const unsigned short* base, int row, int chunk) {
  return as_bf(*(const u16x8*)&base[row * 64 + ((chunk ^ (row & 7)) << 3)]);
}

// same for [rows][128] bf16 tiles (16 chunks/row, 4-bit xor)
__device__ __forceinline__ bf16x8 lds_frag128(const unsigned short* base, int row, int chunk) {
  return as_bf(*(const u16x8*)&base[row * 128 + ((chunk ^ (row & 15)) << 3)]);
}

// ---------------- weight transpose tile + fp32->bf16: dst[c][r] = src[r][c]
__device__ __forceinline__ void transpose_tile(
    const float* __restrict__ src, unsigned short* __restrict__ dst,
    int R, int C, int bx, int by, int tid) {
  __shared__ float t[32][33];
  const int rb = by * 32, cb = bx * 32;
  const int r0 = tid >> 5;   // 0..7
  const int c  = tid & 31;
#pragma unroll
  for (int i = 0; i < 4; ++i)
    t[r0 + i * 8][c] = src[(rb + r0 + i * 8) * C + cb + c];
  __syncthreads();
#pragma unroll
  for (int i = 0; i < 4; ++i)
    dst[(cb + r0 + i * 8) * R + rb + c] = f2bf(t[c][r0 + i * 8]);
}

// ---------------- prep: LN (blocks 0..4095) + weight transposes (4096..8191)
__global__ __launch_bounds__(256) void prep_kernel(
    const float* __restrict__ x, const float* __restrict__ g,
    const float* __restrict__ be, const float* __restrict__ w_qkv,
    const float* __restrict__ w_out, unsigned short* __restrict__ xn,
    unsigned short* __restrict__ wqkvT, unsigned short* __restrict__ woutT) {
  const int bid = blockIdx.x, tid = threadIdx.x;
  if (bid < MROWS) {
    // LayerNorm: one row (1024) per 256-thread block, bf16 out
    const int row = bid;
    const int wave = tid >> 6, lane = tid & 63;
    const float4 v = *(const float4*)&x[row * DIMM + tid * 4];
    float s  = v.x + v.y + v.z + v.w;
    float s2 = v.x * v.x + v.y * v.y + v.z * v.z + v.w * v.w;
#pragma unroll
    for (int o = 32; o >= 1; o >>= 1) { s += __shfl_xor(s, o); s2 += __shfl_xor(s2, o); }
    __shared__ float ps[4], ps2[4];
    if (lane == 0) { ps[wave] = s; ps2[wave] = s2; }
    __syncthreads();
    s  = ps[0] + ps[1] + ps[2] + ps[3];
    s2 = ps2[0] + ps2[1] + ps2[2] + ps2[3];
    const float mu  = s * (1.0f / DIMM);
    const float var = s2 * (1.0f / DIMM) - mu * mu;
    const float rs  = rsqrtf(var + 1e-5f);
    const float4 gg = *(const float4*)&g[tid * 4];
    const float4 bb = *(const float4*)&be[tid * 4];
    u16x4 o;
    o[0] = f2bf((v.x - mu) * rs * gg.x + bb.x);
    o[1] = f2bf((v.y - mu) * rs * gg.y + bb.y);
    o[2] = f2bf((v.z - mu) * rs * gg.z + bb.z);
    o[3] = f2bf((v.w - mu) * rs * gg.w + bb.w);
    *(u16x4*)&xn[row * DIMM + tid * 4] = o;
  } else {
    const int t = bid - MROWS;            // 0..4095
    const int bx = t & 127, by = t >> 7;  // 128 x 32
    if (bx < QKVN / 32) transpose_tile(w_qkv, wqkvT, DIMM, QKVN, bx, by, tid);
    else                transpose_tile(w_out, woutT, DIMM, DIMM, bx - QKVN / 32, by, tid);
  }
}

// ---------------- merged QKV GEMM: 128x128 tiles, single-buffer 32KB LDS,
// 3 blocks/CU co-resident (grid 768). bn 0..15 -> q/k (C^T), 16..23 -> v (C).
__global__ __launch_bounds__(256, 3) void gemm_qkv_kernel(
    const unsigned short* __restrict__ A, const unsigned short* __restrict__ Bt,
    unsigned short* __restrict__ qb, unsigned short* __restrict__ kb,
    unsigned short* __restrict__ vtb) {
  __shared__ __attribute__((aligned(16))) unsigned short As[128 * 64];  // 16 KB
  __shared__ __attribute__((aligned(16))) unsigned short Bs[128 * 64];  // 16 KB
  const int tid = threadIdx.x;
  const int bm = blockIdx.y, bn = blockIdx.x;
  const int lane = tid & 63, wave = tid >> 6;
  const int l15 = lane & 15, quad = lane >> 4;
  const int wm = wave >> 1, wn = wave & 1;
  const int lrow = lane >> 3;
  const int gcol = ((lane & 7) ^ lrow) << 3;
  const unsigned short* Ab = A  + (bm * 128 + wave * 32 + lrow) * DIMM + gcol;
  const unsigned short* Bb = Bt + (bn * 128 + wave * 32 + lrow) * DIMM + gcol;
  const bool swap = (bn < 16);
  f32x4 acc[4][4] = {};

  for (int k0 = 0; k0 < DIMM; k0 += 64) {
#pragma unroll
    for (int j = 0; j < 4; ++j) {
      gl_lds16(Ab + j * 8 * DIMM + k0, &As[(wave * 32 + j * 8) * 64]);
      gl_lds16(Bb + j * 8 * DIMM + k0, &Bs[(wave * 32 + j * 8) * 64]);
    }
    __syncthreads();
#pragma unroll
    for (int kk = 0; kk < 2; ++kk) {
      bf16x8 af[4], bfr[4];
#pragma unroll
      for (int mi = 0; mi < 4; ++mi) af[mi]  = lds_frag(As, wm * 64 + mi * 16 + l15, kk * 4 + quad);
#pragma unroll
      for (int ni = 0; ni < 4; ++ni) bfr[ni] = lds_frag(Bs, wn * 64 + ni * 16 + l15, kk * 4 + quad);
      if (swap) {
#pragma unroll
        for (int mi = 0; mi < 4; ++mi)
#pragma unroll
          for (int ni = 0; ni < 4; ++ni)
            acc[mi][ni] = __builtin_amdgcn_mfma_f32_16x16x32_bf16(bfr[ni], af[mi], acc[mi][ni], 0, 0, 0);
      } else {
#pragma unroll
        for (int mi = 0; mi < 4; ++mi)
#pragma unroll
          for (int ni = 0; ni < 4; ++ni)
            acc[mi][ni] = __builtin_amdgcn_mfma_f32_16x16x32_bf16(af[mi], bfr[ni], acc[mi][ni], 0, 0, 0);
      }
    }
    __syncthreads();
  }

  if (swap) {
    // q/k blocks: C^T -> reg r runs along weight col (dd) -> b64 stores.
    const int colbase = bn * 128 + wn * 64;        // wave-uniform
    const int which = colbase >> 10;               // 0=q, 1=k
    unsigned short* dst = which ? kb : qb;
    const float sc = which ? 1.0f : QSCALE;
#pragma unroll
    for (int mi = 0; mi < 4; ++mi) {
      const int m = bm * 128 + wm * 64 + mi * 16 + l15;   // xn row
      const int bh0 = (m >> 11) * HEADS;
      const int n = m & 2047;
#pragma unroll
      for (int ni = 0; ni < 4; ++ni) {
        const int wc = (colbase & 1023) + ni * 16 + quad * 4;  // r-contig
        const int h = wc >> 6, dd = wc & 63;
        f32x4 v = acc[mi][ni] * sc;
        *(u16x4*)&dst[((bh0 + h) * NSEQ + n) * DHEAD + dd] = cvt4(v);
      }
    }
  } else {
    // v blocks: C -> reg r runs along n -> b64 stores to vt.
    const int colbase = bn * 128 + wn * 64 - 2048;   // v col base, 0..1023
#pragma unroll
    for (int mi = 0; mi < 4; ++mi) {
      const int m0 = bm * 128 + wm * 64 + mi * 16 + quad * 4;   // n, r-contig
      const int bh0 = (m0 >> 11) * HEADS;
      const int n0 = m0 & 2047;
#pragma unroll
      for (int ni = 0; ni < 4; ++ni) {
        const int vcol = colbase + ni * 16 + l15;
        const int h = vcol >> 6, dd = vcol & 63;
        *(u16x4*)&vtb[((bh0 + h) * DHEAD + dd) * NSEQ + n0] = cvt4(acc[mi][ni]);
      }
    }
  }
}

// ---------------- flash attention, transposed-S, fixed-offset softmax.
// block = (bh, 128-row q tile), 4 waves x 32 q rows (2 subtiles of 16);
// per-lane softmax (q = lane&15). Double-buffered K/V staging, ONE barrier
// per kv-iter. p = exp2(s-32); scale cancels in num/denom.  [R5, 53us]
__global__ __launch_bounds__(256, 2) void attn_kernel(
    const unsigned short* __restrict__ qb, const unsigned short* __restrict__ kb,
    const unsigned short* __restrict__ vtb, unsigned short* __restrict__ attn_out) {
  __shared__ __attribute__((aligned(16))) unsigned short Ks[2][64 * 64];   // swizzled
  __shared__ __attribute__((aligned(16))) unsigned short Vts[2][64 * 64];  // swizzled
  __shared__ __attribute__((aligned(16))) unsigned short Ps[4][2][16][72]; // per-wave, per-sub
  const int tid = threadIdx.x, wave = tid >> 6, lane = tid & 63;
  const int l15 = lane & 15, quad = lane >> 4;
  const int bh = blockIdx.x, qt = blockIdx.y;
  const int b = bh >> 4, h = bh & 15;
  const int qbase = qt * 128 + wave * 32;   // this wave's 32 q rows

  // Q fragments (B-operand layout: n=l15=q, k=quad*8+j), q pre-scaled
  bf16x8 aq[2][2];
#pragma unroll
  for (int sub = 0; sub < 2; ++sub) {
    const unsigned short* qrow = qb + (bh * NSEQ + qbase + sub * 16 + l15) * DHEAD;
    aq[sub][0] = as_bf(*(const u16x8*)(qrow + quad * 8));
    aq[sub][1] = as_bf(*(const u16x8*)(qrow + 32 + quad * 8));
  }

  float lsum[2] = {0.f, 0.f};
  f32x4 occ[2][4] = {};   // O^T per sub: d = ct*16+quad*4+r, q = l15

  const int lrow = lane >> 3;
  const int gcol = ((lane & 7) ^ lrow) << 3;
  const unsigned short* Kb = kb  + (bh * NSEQ + wave * 16 + lrow) * DHEAD + gcol;
  const unsigned short* Vb = vtb + (bh * DHEAD + wave * 16 + lrow) * NSEQ + gcol;

  // prologue: stage kv tile 0 into buffer 0
  gl_lds16(Kb,             &Ks[0][(wave * 16) * 64]);
  gl_lds16(Kb + 8 * DHEAD, &Ks[0][(wave * 16 + 8) * 64]);
  gl_lds16(Vb,             &Vts[0][(wave * 16) * 64]);
  gl_lds16(Vb + 8 * NSEQ,  &Vts[0][(wave * 16 + 8) * 64]);

  // the single kv-iter containing this wave's diagonal (both subs share it)
  const int diag_it = qt * 2 + (wave >> 1);

  for (int it = 0; it < NSEQ / 64; ++it) {
    const int cur = it & 1;
    __syncthreads();   // drains this wave's async loads into buf[cur]
    if (it < NSEQ / 64 - 1) {
      const unsigned short* Kn = Kb + (it + 1) * 64 * DHEAD;
      const unsigned short* Vn = Vb + (it + 1) * 64;
      gl_lds16(Kn,             &Ks[cur ^ 1][(wave * 16) * 64]);
      gl_lds16(Kn + 8 * DHEAD, &Ks[cur ^ 1][(wave * 16 + 8) * 64]);
      gl_lds16(Vn,             &Vts[cur ^ 1][(wave * 16) * 64]);
      gl_lds16(Vn + 8 * NSEQ,  &Vts[cur ^ 1][(wave * 16 + 8) * 64]);
    }
    // hoisted fragments, shared by both q-subtiles
    bf16x8 ak[2][4], av[2][4];
#pragma unroll
    for (int kk = 0; kk < 2; ++kk)
#pragma unroll
      for (int ct = 0; ct < 4; ++ct) {
        ak[kk][ct] = lds_frag(&Ks[cur][0],  ct * 16 + l15, kk * 4 + quad);
        av[kk][ct] = lds_frag(&Vts[cur][0], ct * 16 + l15, kk * 4 + quad);
      }
#pragma unroll
    for (int sub = 0; sub < 2; ++sub) {
      // S^T - 32 : col=l15=q, row=quad*4+r=kv offset (per ct tile of 16)
      f32x4 scc[4];
#pragma unroll
      for (int ct = 0; ct < 4; ++ct) scc[ct] = (f32x4){-32.f, -32.f, -32.f, -32.f};
#pragma unroll
      for (int kk = 0; kk < 2; ++kk)
#pragma unroll
        for (int ct = 0; ct < 4; ++ct)
          scc[ct] = __builtin_amdgcn_mfma_f32_16x16x32_bf16(ak[kk][ct], aq[sub][kk], scc[ct], 0, 0, 0);
#pragma unroll
      for (int ct = 0; ct < 4; ++ct)
#pragma unroll
        for (int r = 0; r < 4; ++r) scc[ct][r] = EXP2(scc[ct][r]);

      // diagonal mask (wave-uniform branch; zero BEFORE summing)
      if (it == diag_it) {
        const int kvo_want = (wave & 1) * 32 + sub * 16 + l15;
#pragma unroll
        for (int ct = 0; ct < 4; ++ct)
#pragma unroll
          for (int r = 0; r < 4; ++r)
            if (ct * 16 + quad * 4 + r == kvo_want) scc[ct][r] = 0.f;
      }

      f32x4 ps4 = (scc[0] + scc[1]) + (scc[2] + scc[3]);
      lsum[sub] += (ps4[0] + ps4[1]) + (ps4[2] + ps4[3]);

      // P[q][kv] -> LDS (wave-private slice, same-wave in-order)
#pragma unroll
      for (int ct = 0; ct < 4; ++ct)
        *(u16x4*)&Ps[wave][sub][l15][ct * 16 + quad * 4] = cvt4(scc[ct]);

      // O^T += V^T P^T : A=Vt (m=d,k=kv), B=P (n=q,k=kv)
#pragma unroll
      for (int kk = 0; kk < 2; ++kk) {
        bf16x8 bp = as_bf(*(const u16x8*)&Ps[wave][sub][l15][kk * 32 + quad * 8]);
#pragma unroll
        for (int ct = 0; ct < 4; ++ct)
          occ[sub][ct] = __builtin_amdgcn_mfma_f32_16x16x32_bf16(av[kk][ct], bp, occ[sub][ct], 0, 0, 0);
      }
    }
  }
  // epilogue: O^T / l -> attn_out[b*N + q][h*64 + d], d-contiguous 8B stores
#pragma unroll
  for (int sub = 0; sub < 2; ++sub) {
    float l = lsum[sub];
    l += __shfl_xor(l, 16);
    l += __shfl_xor(l, 32);
    const float rl = __builtin_amdgcn_rcpf(l);
    const int qg = qbase + sub * 16 + l15;
#pragma unroll
    for (int ct = 0; ct < 4; ++ct) {
      f32x4 ov = occ[sub][ct] * rl;
      *(u16x4*)&attn_out[(b * NSEQ + qg) * DIMM + h * DHEAD + ct * 16 + quad * 4] = cvt4(ov);
    }
  }
}

// ---------------- output projection (C^T): [4096,1024] @ woutT[1024,1024] -> fp32
// M64 x N128 tiles, BK=128 (8 K-iters, 32 MFMA/wave/barrier), single-buffer
// 48KB LDS, grid (8,64)=512 = 2 blocks/CU exact.
__global__ __launch_bounds__(256, 2) void gemm_out_kernel(
    const unsigned short* __restrict__ A,   // attn bf16 [4096,1024]
    const unsigned short* __restrict__ Bt,  // woutT bf16 [1024,1024]
    float* __restrict__ out) {
  __shared__ __attribute__((aligned(16))) unsigned short As[64 * 128];   // 16 KB
  __shared__ __attribute__((aligned(16))) unsigned short Bs[128 * 128];  // 32 KB
  const int tid = threadIdx.x;
  const int bm = blockIdx.y, bn = blockIdx.x;
  const int lane = tid & 63, wave = tid >> 6;
  const int l15 = lane & 15, quad = lane >> 4;
  const int wm = wave >> 1, wn = wave & 1;
  // staging lane mapping for 256B rows: 4 rows per gl_lds16
  const int rl4 = lane >> 4;   // row within instr, 0..3
  const int cp  = lane & 15;   // chunk position, 0..15
  const int cx  = cp ^ rl4;    // base xor (LDS[row][p] = G[row][p ^ (row&15)])
  const int Arow0 = bm * 64 + wave * 16 + rl4;
  const int Brow0 = bn * 128 + wave * 32 + rl4;
  f32x4 acc[2][4] = {};

  for (int it = 0; it < 8; ++it) {
    const int k0 = it * 128;
    // stage A: 64 rows x 128k (4 instrs/wave), B: 128 rows (8 instrs/wave)
#pragma unroll
    for (int j = 0; j < 4; ++j)
      gl_lds16(A + (Arow0 + j * 4) * DIMM + k0 + ((cx ^ (j << 2)) << 3),
               &As[(wave * 16 + j * 4) * 128]);
#pragma unroll
    for (int j = 0; j < 8; ++j)
      gl_lds16(Bt + (Brow0 + j * 4) * DIMM + k0 + ((cx ^ ((j & 3) << 2)) << 3),
               &Bs[(wave * 32 + j * 4) * 128]);
    __syncthreads();
#pragma unroll
    for (int kk = 0; kk < 4; ++kk) {
      bf16x8 af[2], bfr[4];
#pragma unroll
      for (int mi = 0; mi < 2; ++mi) af[mi]  = lds_frag128(As, wm * 32 + mi * 16 + l15, kk * 4 + quad);
#pragma unroll
      for (int ni = 0; ni < 4; ++ni) bfr[ni] = lds_frag128(Bs, wn * 64 + ni * 16 + l15, kk * 4 + quad);
#pragma unroll
      for (int mi = 0; mi < 2; ++mi)
#pragma unroll
        for (int ni = 0; ni < 4; ++ni)
          acc[mi][ni] = __builtin_amdgcn_mfma_f32_16x16x32_bf16(bfr[ni], af[mi], acc[mi][ni], 0, 0, 0);
    }
    __syncthreads();
  }
  // C^T epilogue: col=l15 -> out row m; row(quad*4+r, r-contig) -> out col.
#pragma unroll
  for (int mi = 0; mi < 2; ++mi) {
    const int m = bm * 64 + wm * 32 + mi * 16 + l15;   // attn row
#pragma unroll
    for (int ni = 0; ni < 4; ++ni) {
      const int col = bn * 128 + wn * 64 + ni * 16 + quad * 4;  // r-contig
      *(f32x4*)&out[m * DIMM + col] = acc[mi][ni];
    }
  }
}

extern "C" void kernel_launch(void* const* d_in, const int* in_sizes, int n_in,
                              void* d_out, int out_size, void* d_ws, size_t ws_size,
                              hipStream_t stream) {
  const float* x     = (const float*)d_in[0];
  const float* gamma = (const float*)d_in[1];
  const float* beta  = (const float*)d_in[2];
  const float* w_qkv = (const float*)d_in[3];  // [1024, 3072]
  const float* w_out = (const float*)d_in[4];  // [1024, 1024]
  float* out = (float*)d_out;

  char* ws = (char*)d_ws;
  unsigned short* xn    = (unsigned short*)(ws);                        // 8 MB
  unsigned short* wqkvT = (unsigned short*)(ws + 8388608);              // 6 MB
  unsigned short* woutT = (unsigned short*)(ws + 14680064);             // 2 MB
  unsigned short* qbuf  = (unsigned short*)(ws + 16777216);             // 8 MB
  unsigned short* kbuf  = (unsigned short*)(ws + 25165824);             // 8 MB
  unsigned short* vtbuf = (unsigned short*)(ws + 33554432);             // 8 MB
  unsigned short* attnb = (unsigned short*)(ws + 41943040);             // 8 MB

  prep_kernel<<<MROWS + (QKVN + DIMM) / 32 * (DIMM / 32), 256, 0, stream>>>(
      x, gamma, beta, w_qkv, w_out, xn, wqkvT, woutT);
  gemm_qkv_kernel<<<dim3(24, MROWS / 128), 256, 0, stream>>>(xn, wqkvT, qbuf, kbuf, vtbuf);
  attn_kernel<<<dim3(BATCH * HEADS, NSEQ / 128), 256, 0, stream>>>(qbuf, kbuf, vtbuf, attnb);
  gemm_out_kernel<<<dim3(DIMM / 128, MROWS / 64), 256, 0, stream>>>(attnb, woutT, out);
}